// Round 11
// baseline (460.047 us; speedup 1.0000x reference)
//
#include <hip/hip_runtime.h>

// ---------- types ----------
typedef short s16x8 __attribute__((ext_vector_type(8)));   // 8 bf16 (4 VGPRs)
typedef float f32x4 __attribute__((ext_vector_type(4)));

static __device__ __forceinline__ unsigned short f2bf(float f) {
  unsigned u = __builtin_bit_cast(unsigned, f);
  return (unsigned short)((u + 0x7FFFu + ((u >> 16) & 1u)) >> 16);   // RNE; finite
}

// async global->LDS, 16B per lane; LDS dst is wave-uniform base + lane*16
#define GLL16(G, L) __builtin_amdgcn_global_load_lds( \
    (const __attribute__((address_space(1))) void*)(G), \
    (__attribute__((address_space(3))) void*)(L), 16, 0, 0)

#define KD 512
// B=16, T=512, C=19, E=512, H=8, HD=64; groups = 8192, rows = 155648 = 1216*128.
// Fragment layout: frag (tile16, ktile32) = 1 KB: lane lf = (row&15) + 16*jc holds
// 16 B (8 bf16) of [row][ktile*32 + jc*8]. MFMA A/B reads are lane*16-linear.

// ---------- kernel: weights fp32 -> bf16 fragment layout (rows 0..511 wq, 512..1023 wk) ----------
__global__ __launch_bounds__(256)
void k_convw(const float* __restrict__ wq, const float* __restrict__ wk,
             unsigned short* __restrict__ Wf) {
  int gid = blockIdx.x * 256 + threadIdx.x;   // 65536 threads
  int nt = gid >> 10, slot = gid & 1023;
  int kt = slot >> 6, lf = slot & 63;
  int f  = nt * 16 + (lf & 15);
  int jc = lf >> 4;
  const float* p = ((f < 512) ? (wq + (long)f * KD) : (wk + (long)(f - 512) * KD)) + kt * 32 + jc * 8;
  float4 v0 = *(const float4*)p;
  float4 v1 = *(const float4*)(p + 4);
  s16x8 o;
  o[0]=(short)f2bf(v0.x); o[1]=(short)f2bf(v0.y); o[2]=(short)f2bf(v0.z); o[3]=(short)f2bf(v0.w);
  o[4]=(short)f2bf(v1.x); o[5]=(short)f2bf(v1.y); o[6]=(short)f2bf(v1.z); o[7]=(short)f2bf(v1.w);
  *(s16x8*)(Wf + ((long)nt * 16 + kt) * 512 + (long)lf * 8) = o;
}

// ---------- kernel: QK = eeg @ [Wq^T | Wk^T] + bias ----------
// v7 = R10 2-phase skeleton, but A is staged DIRECTLY from fp32 eeg (conva kernel
// deleted): per step each thread loads 16 floats (4x float4, issued at top of step
// for t+1), converts after the MFMA block, writes 2x ds_write_b128 into the frag
// layout (write pattern spreads 8 lanes per 4-bank group: conflict-free).
// B stays global_load_lds from frag-ordered Wf. launch_bounds(256,3): ~170 regs/wave
// so 64 AGPR + ~85 VGPR fit with ZERO spill (R8 lesson: never cap regs in use).
__global__ __launch_bounds__(256, 3)
void k_gemm(const float* __restrict__ eeg, const unsigned short* __restrict__ Wf,
            const float* __restrict__ bq, const float* __restrict__ bk,
            unsigned short* __restrict__ QK, long grow0) {
  __shared__ unsigned short Abuf[2][8 * 512];   // per buffer: 8 frags (msub 0..7), BK=32
  __shared__ unsigned short Bbuf[2][8 * 512];   // per buffer: 8 frags (nsub 0..7)

  const int tid  = threadIdx.x;
  const int lane = tid & 63;
  const int wid  = tid >> 6;      // 0..3
  const int wr   = wid >> 1, wc = wid & 1;
  const int rlo  = lane & 15, rhi = lane >> 4;

  // XCD-chunked swizzle (verified R8/R9: A panel fetched ~once per XCD).
  const int cpx = gridDim.x >> 3;
  const int L   = (blockIdx.x & 7) * cpx + (blockIdx.x >> 3);
  const int mb  = L >> 3;
  const int bn  = L & 7;

  // ---- A reg-staging geometry: thread = (row sr, k-half sh): 16 floats/step ----
  const int sr = tid >> 1;            // 0..127
  const int sh = tid & 1;             // k-offset sh*16
  const float* abase = eeg + (grow0 + (long)mb * 128 + sr) * KD + sh * 16;
  // LDS elem offset: frag msub = sr>>4, lane lf = (sr&15) + 32*sh (+16 for 2nd half)
  const int aoff = (sr >> 4) * 512 + ((sr & 15) + 32 * sh) * 8;

  // ---- B staging: wave wid stages frags {2*wid, 2*wid+1} via global_load_lds ----
#define STAGE_B(T, BUF) do { \
    const int ns_ = wid * 2; \
    const unsigned short* g0_ = Wf + ((long)(bn * 8 + ns_) * 16 + (T)) * 512 + lane * 8; \
    GLL16(g0_, &Bbuf[(BUF)][ns_ * 512]); \
    const unsigned short* g1_ = Wf + ((long)(bn * 8 + ns_ + 1) * 16 + (T)) * 512 + lane * 8; \
    GLL16(g1_, &Bbuf[(BUF)][(ns_ + 1) * 512]); \
  } while (0)

#define CVT_WRITE_A(BUF) do { \
    s16x8 o0_, o1_; \
    o0_[0]=(short)f2bf(a0.x); o0_[1]=(short)f2bf(a0.y); o0_[2]=(short)f2bf(a0.z); o0_[3]=(short)f2bf(a0.w); \
    o0_[4]=(short)f2bf(a1.x); o0_[5]=(short)f2bf(a1.y); o0_[6]=(short)f2bf(a1.z); o0_[7]=(short)f2bf(a1.w); \
    o1_[0]=(short)f2bf(a2.x); o1_[1]=(short)f2bf(a2.y); o1_[2]=(short)f2bf(a2.z); o1_[3]=(short)f2bf(a2.w); \
    o1_[4]=(short)f2bf(a3.x); o1_[5]=(short)f2bf(a3.y); o1_[6]=(short)f2bf(a3.z); o1_[7]=(short)f2bf(a3.w); \
    *(s16x8*)&Abuf[(BUF)][aoff]       = o0_; \
    *(s16x8*)&Abuf[(BUF)][aoff + 128] = o1_; \
  } while (0)

  f32x4 acc[4][4] = {};

  // ---- prologue: stage tile 0 ----
  {
    float4 a0 = *(const float4*)(abase + 0);
    float4 a1 = *(const float4*)(abase + 4);
    float4 a2 = *(const float4*)(abase + 8);
    float4 a3 = *(const float4*)(abase + 12);
    STAGE_B(0, 0);
    CVT_WRITE_A(0);
  }
  __syncthreads();   // vmcnt(0)+lgkmcnt(0) drain: buf0 ready

#pragma unroll 1
  for (int t = 0; t < 16; ++t) {
    const int cur = t & 1;
    float4 a0, a1, a2, a3;
    const bool pre = (t < 15);
    if (pre) {
      const float* ap = abase + (t + 1) * 32;
      a0 = *(const float4*)(ap + 0);      // issue-early: consumed after MFMA
      a1 = *(const float4*)(ap + 4);
      a2 = *(const float4*)(ap + 8);
      a3 = *(const float4*)(ap + 12);
      STAGE_B(t + 1, cur ^ 1);
    }

    s16x8 af[4], bfr[4];
#pragma unroll
    for (int m = 0; m < 4; ++m)
      af[m] = *(const s16x8*)&Abuf[cur][(wr * 4 + m) * 512 + lane * 8];
#pragma unroll
    for (int n = 0; n < 4; ++n)
      bfr[n] = *(const s16x8*)&Bbuf[cur][(wc * 4 + n) * 512 + lane * 8];
#pragma unroll
    for (int m = 0; m < 4; ++m)
#pragma unroll
      for (int n = 0; n < 4; ++n)
        acc[m][n] = __builtin_amdgcn_mfma_f32_16x16x32_bf16(af[m], bfr[n], acc[m][n], 0, 0, 0);

    if (pre) CVT_WRITE_A(cur ^ 1);   // waits the early A loads, writes next buffer
    __syncthreads();                 // B gload_lds landed + A ds_writes visible
  }
#undef STAGE_B
#undef CVT_WRITE_A

  // ---- epilogue: bias + bf16 store ----
#pragma unroll
  for (int n = 0; n < 4; ++n) {
    int colg = bn * 128 + wc * 64 + n * 16 + rlo;
    float bias = (colg < 512) ? bq[colg] : bk[colg - 512];
#pragma unroll
    for (int m = 0; m < 4; ++m) {
      long rl = (long)mb * 128 + wr * 64 + m * 16 + (rhi << 2);
#pragma unroll
      for (int j = 0; j < 4; ++j)
        QK[(rl + j) * 1024 + colg] = f2bf(acc[m][n][j] + bias);
    }
  }
}

// ---------- kernel: per-group attention -> atomic strength accumulation ----------
__global__ __launch_bounds__(256, 3)
void k_attn(const unsigned short* __restrict__ QK, float* __restrict__ acc, int g0) {
  __shared__ unsigned short Qs[19][1032];
  __shared__ float Sc[8][19][20];
  __shared__ float red[256];

  const int tid  = threadIdx.x;
  const int lane = tid & 63;
  const int wid  = tid >> 6;
  const long gl  = blockIdx.x;

  const unsigned short* src = QK + gl * 19 * 1024;
  for (int c = tid; c < 2432; c += 256) {
    int row = c >> 7, c8 = (c & 127) << 3;
    *(s16x8*)&Qs[row][c8] = *(const s16x8*)(src + row * 1024 + c8);
  }
  __syncthreads();

  const int rlo = lane & 15, rhi = lane >> 4;
  const s16x8 z8 = {};
#pragma unroll
  for (int hh = 0; hh < 2; ++hh) {
    const int h = wid * 2 + hh;
    f32x4 s[2][2] = {};
#pragma unroll
    for (int ks = 0; ks < 2; ++ks) {
      s16x8 qa[2], kb[2];
#pragma unroll
      for (int mi = 0; mi < 2; ++mi) {
        int r = mi * 16 + rlo;
        qa[mi] = (r < 19) ? *(const s16x8*)&Qs[r][h * 64 + ks * 32 + rhi * 8] : z8;
        kb[mi] = (r < 19) ? *(const s16x8*)&Qs[r][512 + h * 64 + ks * 32 + rhi * 8] : z8;
      }
#pragma unroll
      for (int mi = 0; mi < 2; ++mi)
#pragma unroll
        for (int nj = 0; nj < 2; ++nj)
          s[mi][nj] = __builtin_amdgcn_mfma_f32_16x16x32_bf16(qa[mi], kb[nj], s[mi][nj], 0, 0, 0);
    }
#pragma unroll
    for (int mi = 0; mi < 2; ++mi)
#pragma unroll
      for (int nj = 0; nj < 2; ++nj)
#pragma unroll
        for (int j = 0; j < 4; ++j) {
          int r = mi * 16 + rhi * 4 + j, c = nj * 16 + rlo;
          if (r < 19 && c < 19) Sc[h][r][c] = s[mi][nj][j] * 0.125f;
        }
  }
  __syncthreads();

  float p = 0.f;
  if (tid < 152) {
    int h = tid / 19, i = tid - h * 19;
    float sv[19];
    float mx = -1e30f;
#pragma unroll
    for (int j = 0; j < 19; ++j) { sv[j] = Sc[h][i][j]; mx = fmaxf(mx, sv[j]); }
    float sum = 0.f, up = 0.f;
#pragma unroll
    for (int j = 0; j < 19; ++j) {
      float e = __expf(sv[j] - mx);
      sum += e;
      if (j > i) up += e;
    }
    p = up / sum;
  }
  red[tid] = p;
  __syncthreads();
  for (int off = 128; off > 0; off >>= 1) {
    if (tid < off) red[tid] += red[tid + off];
    __syncthreads();
  }
  if (tid == 0) {
    int b = (g0 + (int)blockIdx.x) >> 9;
    atomicAdd(&acc[b], red[0]);
  }
}

// ---------- kernel: finalize out[b] = clip(acc[b] / (8*171*512), 0, 1) ----------
__global__ void k_fin(const float* __restrict__ acc, float* __restrict__ out) {
  int t = threadIdx.x;
  if (t < 16) {
    float v = acc[t] * (1.0f / 700416.0f);
    out[t] = fminf(1.0f, fmaxf(0.0f, v));
  }
}

// ---------- host ----------
extern "C" void kernel_launch(void* const* d_in, const int* in_sizes, int n_in,
                              void* d_out, int out_size, void* d_ws, size_t ws_size,
                              hipStream_t stream) {
  const float* eeg = (const float*)d_in[0];
  const float* wq  = (const float*)d_in[1];
  const float* wk  = (const float*)d_in[2];
  const float* bq  = (const float*)d_in[3];
  const float* bk  = (const float*)d_in[4];
  float* out = (float*)d_out;

  char* ws = (char*)d_ws;
  unsigned short* Wf = (unsigned short*)ws;          // 1 MiB frag-layout weights
  float* acc = (float*)(ws + (1 << 20));             // 64 B accumulators
  long off = (1 << 20) + 256;

  // per-group QK: 19*1024*2 = 38912 B. Single chunk when ws permits (R7 lesson).
  long avail = (long)ws_size - off;
  long G = avail / 38912;
  G = (G / 128) * 128;
  if (G > 8192) G = 8192;
  if (G < 128) G = 128;
  unsigned short* QKb = (unsigned short*)(ws + off);

  hipMemsetAsync(acc, 0, 64, stream);
  k_convw<<<256, 256, 0, stream>>>(wq, wk, Wf);

  for (int g0 = 0; g0 < 8192; g0 += (int)G) {
    int cg = 8192 - g0; if (cg > (int)G) cg = (int)G;
    int rows = cg * 19;              // cg multiple of 128 -> rows multiple of 2432
    k_gemm<<<(rows / 128) * 8, 256, 0, stream>>>(eeg, Wf, bq, bk, QKb, (long)g0 * 19);
    k_attn<<<cg, 256, 0, stream>>>(QKb, acc, g0);
  }
  k_fin<<<1, 64, 0, stream>>>(acc, out);
}